// Round 6
// baseline (541.471 us; speedup 1.0000x reference)
//
#include <hip/hip_runtime.h>

typedef unsigned short u16;
typedef __attribute__((ext_vector_type(8))) short short8;
typedef __attribute__((ext_vector_type(4))) float floatx4;

#define LOG2E 1.44269504f

__device__ __forceinline__ u16 f2bf(float x) {
  union { float f; unsigned u; } un; un.f = x;
  unsigned r = un.u + 0x7fffu + ((un.u >> 16) & 1u);
  return (u16)(r >> 16);
}
__device__ __forceinline__ float bf2f(u16 h) {
  union { unsigned u; float f; } un; un.u = ((unsigned)h) << 16;
  return un.f;
}
__device__ __forceinline__ void gld16(const u16* g, u16* l) {
  __builtin_amdgcn_global_load_lds((__attribute__((address_space(1))) void*)g,
                                   (__attribute__((address_space(3))) void*)l, 16, 0, 0);
}

// ---------------- weight transpose + fp32->bf16 : in (K,N) -> out (N,K) ----------------
__global__ __launch_bounds__(256) void wtrans_kernel(const float* __restrict__ in,
                                                     u16* __restrict__ out, int K, int N) {
  __shared__ float tile[32][33];
  int tx = threadIdx.x, ty = threadIdx.y;
  int n0 = blockIdx.x * 32, k0 = blockIdx.y * 32;
#pragma unroll
  for (int i = 0; i < 4; i++) {
    int kk = ty + i * 8;
    tile[kk][tx] = in[(size_t)(k0 + kk) * N + n0 + tx];
  }
  __syncthreads();
#pragma unroll
  for (int i = 0; i < 4; i++) {
    int nn = ty + i * 8;
    out[(size_t)(n0 + nn) * K + k0 + tx] = f2bf(tile[tx][nn]);
  }
}

// ---------------- PE add: q_in = bf16(q + pe), k_in = bf16(k + pe) ----------------
__global__ __launch_bounds__(256) void pe_add_kernel(const float* __restrict__ q,
                                                     const float* __restrict__ k,
                                                     u16* __restrict__ qb, u16* __restrict__ kb) {
  size_t flat = ((size_t)blockIdx.x * 256 + threadIdx.x) * 4;
  int d0 = (int)(flat & 511);
  int t = (int)((flat >> 9) & 511);
  const float4 qv = *(const float4*)(q + flat);
  const float4 kv = *(const float4*)(k + flat);
  float pe[4];
#pragma unroll
  for (int i = 0; i < 4; i++) {
    int d = d0 + i;
    int j = (d < 256) ? d : d - 256;
    float f = exp2f((float)j * -0.05190512648f);  // -log2(10000)/256
    float arg = (float)t * f;
    pe[i] = (d < 256) ? cosf(arg) : sinf(arg);
  }
  u16 qo[4], ko[4];
  qo[0] = f2bf(qv.x + pe[0]); qo[1] = f2bf(qv.y + pe[1]);
  qo[2] = f2bf(qv.z + pe[2]); qo[3] = f2bf(qv.w + pe[3]);
  ko[0] = f2bf(kv.x + pe[0]); ko[1] = f2bf(kv.y + pe[1]);
  ko[2] = f2bf(kv.z + pe[2]); ko[3] = f2bf(kv.w + pe[3]);
  *(uint2*)(qb + flat) = *(const uint2*)qo;
  *(uint2*)(kb + flat) = *(const uint2*)ko;
}

// ---------------- bf16 GEMM, BK=64: C = A(MxK) @ Bt(NxK)^T ----------------
// 1-D grid, XCD-swizzled; optional split-K (KS slices).
// DUAL: second half of grid computes C2 = A2 @ Bt2 (independent problem, same shape).
// EPI: 0 = store bf16 C; 2 = relu + column-sum -> atomicAdd outp[b*N + col] (no C store);
//      3 = store transposed per-head: C[((b*8+h)*64+d)*512 + s]  (V^T for attention)
template <int EPI, int DUAL>
__global__ __launch_bounds__(256) void gemm_bt(const u16* __restrict__ A, const u16* __restrict__ Bt,
                                               u16* __restrict__ C, int NX, int KS, int N, int K,
                                               float* __restrict__ outp,
                                               const u16* __restrict__ A2, const u16* __restrict__ Bt2,
                                               u16* __restrict__ C2) {
  __shared__ u16 Alds[128 * 64];
  __shared__ u16 Blds[128 * 64];
  const int tid = threadIdx.x;
  const int lane = tid & 63, w = tid >> 6;
  const int quad = lane >> 4, cl = lane & 15;
  const int wm = w >> 1, wn = w & 1;
  int L = blockIdx.x;
  if (DUAL) {
    int half = gridDim.x >> 1;
    if (L >= half) { L -= half; A = A2; Bt = Bt2; C = C2; }
  }
  const int xcd = L & 7, s = L >> 3;
  const int nx = s % NX;
  const int t2 = s / NX;
  const int ksl = t2 % KS;
  const int rgrp = t2 / KS;
  const int tm = (rgrp * 8 + xcd) * 128;
  const int tn = nx * 128;
  const int kbase = ksl * (K / KS);
  floatx4 acc[4][4] = {};
  const int nk = (K / KS) >> 6;
  const int srow = lane >> 3;        // row within 8-row chunk
  const int sg = (lane & 7) ^ srow;  // swizzled global K-group
  for (int ks = 0; ks < nk; ks++) {
    __syncthreads();
    const int k0 = kbase + (ks << 6);
#pragma unroll
    for (int i = 0; i < 4; i++) {
      int c = w * 4 + i;
      int row = c * 8 + srow;
      gld16(A + ((size_t)(tm + row) * K + k0 + sg * 8), &Alds[c * 512]);
      gld16(Bt + ((size_t)(tn + row) * K + k0 + sg * 8), &Blds[c * 512]);
    }
    __syncthreads();
#pragma unroll
    for (int kh = 0; kh < 2; kh++) {
      short8 af[4], bfr[4];
      const int ga = (((kh << 2) + quad) ^ (cl & 7)) * 8;
#pragma unroll
      for (int f = 0; f < 4; f++) {
        af[f] = *(const short8*)&Alds[(wm * 64 + f * 16 + cl) * 64 + ga];
        bfr[f] = *(const short8*)&Blds[(wn * 64 + f * 16 + cl) * 64 + ga];
      }
#pragma unroll
      for (int fm = 0; fm < 4; fm++)
#pragma unroll
        for (int fn = 0; fn < 4; fn++)
          acc[fm][fn] = __builtin_amdgcn_mfma_f32_16x16x32_bf16(af[fm], bfr[fn], acc[fm][fn], 0, 0, 0);
    }
  }
  if constexpr (EPI == 0) {
#pragma unroll
    for (int fm = 0; fm < 4; fm++)
#pragma unroll
      for (int fn = 0; fn < 4; fn++)
#pragma unroll
        for (int r = 0; r < 4; r++) {
          int row = tm + wm * 64 + fm * 16 + quad * 4 + r;
          int col = tn + wn * 64 + fn * 16 + cl;
          C[(size_t)row * N + col] = f2bf(acc[fm][fn][r]);
        }
  } else if constexpr (EPI == 2) {
    // relu + column-sum over this block's 128 rows -> atomicAdd into outp[b*N + col]
    __shared__ float red[256];
    float csum[4] = {0.f, 0.f, 0.f, 0.f};
#pragma unroll
    for (int fm = 0; fm < 4; fm++)
#pragma unroll
      for (int fn = 0; fn < 4; fn++)
#pragma unroll
        for (int r = 0; r < 4; r++) csum[fn] += fmaxf(acc[fm][fn][r], 0.0f);
#pragma unroll
    for (int fn = 0; fn < 4; fn++) {
      csum[fn] += __shfl_xor(csum[fn], 16);
      csum[fn] += __shfl_xor(csum[fn], 32);
    }
    __syncthreads();
    if (quad == 0) {
#pragma unroll
      for (int fn = 0; fn < 4; fn++) red[wm * 128 + wn * 64 + fn * 16 + cl] = csum[fn];
    }
    __syncthreads();
    if (tid < 128) {
      int wn2 = tid >> 6, c2 = tid & 63;
      float tot = red[wn2 * 64 + c2] + red[128 + wn2 * 64 + c2];
      int b = tm >> 9;
      atomicAdd(outp + (size_t)b * N + tn + wn2 * 64 + c2, tot);
    }
  } else {  // EPI == 3: transposed per-head store (V^T)
    __shared__ u16 Tr[128][130];
#pragma unroll
    for (int fm = 0; fm < 4; fm++)
#pragma unroll
      for (int fn = 0; fn < 4; fn++)
#pragma unroll
        for (int r = 0; r < 4; r++) {
          int row = wm * 64 + fm * 16 + quad * 4 + r;
          int col = wn * 64 + fn * 16 + cl;
          Tr[col][row] = f2bf(acc[fm][fn][r]);
        }
    __syncthreads();
    int col = tid >> 1, half = tid & 1;
    int b = tm >> 9, gcol = tn + col;
    int h = gcol >> 6, d = gcol & 63;
    int s0 = (tm & 511) + half * 64;
    u16* dst = C + ((size_t)((b * 8 + h) * 64 + d) * 512 + s0);
    const u16* src = &Tr[col][half * 64];
#pragma unroll
    for (int j = 0; j < 8; j++) *(short8*)(dst + j * 8) = *(const short8*)(src + j * 8);
  }
}

// ---------------- ffn2 via mean-commutation: outp[b,:] += (sums[b,:] @ fw2) / 512 ----------------
__global__ __launch_bounds__(256) void ffn2_mean_kernel(const float* __restrict__ sums,
                                                        const float* __restrict__ fw2,
                                                        float* __restrict__ outp) {
  __shared__ float s[2048];
  int b = blockIdx.x, tid = threadIdx.x;
#pragma unroll
  for (int i = 0; i < 8; i++) s[i * 256 + tid] = sums[(size_t)b * 2048 + i * 256 + tid];
  __syncthreads();
  float a0 = 0.f, a1 = 0.f;
#pragma unroll 8
  for (int f = 0; f < 2048; f++) {
    float sv = s[f];
    a0 += sv * fw2[(size_t)f * 512 + tid];
    a1 += sv * fw2[(size_t)f * 512 + 256 + tid];
  }
  atomicAdd(outp + b * 512 + tid, a0 * (1.0f / 512.0f));
  atomicAdd(outp + b * 512 + 256 + tid, a1 * (1.0f / 512.0f));
}

// ---------------- flash attention + residual + column-sum of result into outp ----------------
__global__ __launch_bounds__(256) void attn_kernel(const u16* __restrict__ qp, const u16* __restrict__ kp,
                                                   const u16* __restrict__ vT, const u16* __restrict__ qin,
                                                   u16* __restrict__ resout, const int* __restrict__ qlen,
                                                   const int* __restrict__ klen, float* __restrict__ outp) {
  __shared__ u16 Klds[128 * 64];
  __shared__ u16 Vlds[64 * 128];
  __shared__ u16 Plds[4][16 * 136];
  __shared__ float Csum[4][64];
  int bid = blockIdx.x;
  int qt = bid & 7, h = (bid >> 3) & 7, b = bid >> 6;
  int tid = threadIdx.x, lane = tid & 63, w = tid >> 6;
  int quad = lane >> 4, cl = lane & 15;
  int kl = klen[b], ql = qlen[b];
  int q0 = qt * 64 + w * 16;

  if (qt * 64 >= ql) {
    int c = tid & 63, r0 = (tid >> 6) * 16;
    float s = 0.f;
#pragma unroll
    for (int i = 0; i < 16; i++) {
      size_t idx = ((size_t)(b * 512 + qt * 64 + r0 + i) * 512) + h * 64 + c;
      u16 val = qin[idx];
      resout[idx] = val;
      s += bf2f(val);
    }
    Csum[w][c] = s;
    __syncthreads();
    if (tid < 64) {
      float t = Csum[0][tid] + Csum[1][tid] + Csum[2][tid] + Csum[3][tid];
      atomicAdd(outp + b * 512 + h * 64 + tid, t * (1.0f / 512.0f));
    }
    return;
  }
  bool wactive = q0 < ql;

  short8 qfrag[2];
#pragma unroll
  for (int ks = 0; ks < 2; ks++)
    qfrag[ks] = *(const short8*)(qp + ((size_t)(b * 512 + q0 + cl) * 512 + h * 64 + ks * 32 + quad * 8));
  float m_r[4], l_r[4];
  floatx4 o[4] = {};
#pragma unroll
  for (int r = 0; r < 4; r++) { m_r[r] = -3.0e38f; l_r[r] = 0.f; }

  int nkt = (kl + 127) >> 7;
  for (int kt = 0; kt < nkt; kt++) {
    __syncthreads();
#pragma unroll
    for (int i = 0; i < 4; i++) {
      int c = w * 4 + i;
      int row = c * 8 + (lane >> 3);
      int gc = (lane & 7) ^ (row & 7);
      gld16(kp + ((size_t)(b * 512 + kt * 128 + row) * 512 + h * 64 + gc * 8), &Klds[c * 512]);
    }
#pragma unroll
    for (int i = 0; i < 4; i++) {
      int c = w * 4 + i;
      int row = c * 4 + (lane >> 4);
      int gc = (lane & 15) ^ (row & 7);
      gld16(vT + ((size_t)((b * 8 + h) * 64 + row) * 512 + kt * 128 + gc * 8), &Vlds[c * 512]);
    }
    __syncthreads();
    if (!wactive) continue;
    floatx4 sacc[8] = {};
#pragma unroll
    for (int f = 0; f < 8; f++) {
      int krow = f * 16 + cl;
#pragma unroll
      for (int ks = 0; ks < 2; ks++) {
        int kc = ks * 4 + quad;
        short8 kf = *(const short8*)&Klds[krow * 64 + ((kc ^ (cl & 7)) * 8)];
        sacc[f] = __builtin_amdgcn_mfma_f32_16x16x32_bf16(qfrag[ks], kf, sacc[f], 0, 0, 0);
      }
    }
    float mnew[4];
#pragma unroll
    for (int r = 0; r < 4; r++) mnew[r] = m_r[r];
#pragma unroll
    for (int f = 0; f < 8; f++) {
      int key = kt * 128 + f * 16 + cl;
      bool ok = key < kl;
#pragma unroll
      for (int r = 0; r < 4; r++) {
        float v = ok ? sacc[f][r] * 0.125f : -4294967296.0f;
        sacc[f][r] = v;
        mnew[r] = fmaxf(mnew[r], v);
      }
    }
#pragma unroll
    for (int mk = 1; mk <= 8; mk <<= 1)
#pragma unroll
      for (int r = 0; r < 4; r++) mnew[r] = fmaxf(mnew[r], __shfl_xor(mnew[r], mk));
    float alpha[4], lad[4];
#pragma unroll
    for (int r = 0; r < 4; r++) {
      alpha[r] = exp2f((m_r[r] - mnew[r]) * LOG2E);
      lad[r] = 0.f;
      m_r[r] = mnew[r];
    }
#pragma unroll
    for (int f = 0; f < 8; f++)
#pragma unroll
      for (int r = 0; r < 4; r++) {
        float p = exp2f((sacc[f][r] - mnew[r]) * LOG2E);
        lad[r] += p;
        Plds[w][(quad * 4 + r) * 136 + f * 16 + cl] = f2bf(p);
      }
#pragma unroll
    for (int mk = 1; mk <= 8; mk <<= 1)
#pragma unroll
      for (int r = 0; r < 4; r++) lad[r] += __shfl_xor(lad[r], mk);
#pragma unroll
    for (int r = 0; r < 4; r++) l_r[r] = l_r[r] * alpha[r] + lad[r];
#pragma unroll
    for (int fd = 0; fd < 4; fd++)
#pragma unroll
      for (int r = 0; r < 4; r++) o[fd][r] *= alpha[r];
#pragma unroll
    for (int k2 = 0; k2 < 4; k2++) {
      short8 pf = *(const short8*)&Plds[w][cl * 136 + k2 * 32 + quad * 8];
#pragma unroll
      for (int fd = 0; fd < 4; fd++) {
        int vrow = fd * 16 + cl;
        int sc = k2 * 4 + quad;
        short8 vf = *(const short8*)&Vlds[vrow * 128 + ((sc ^ (cl & 7)) * 8)];
        o[fd] = __builtin_amdgcn_mfma_f32_16x16x32_bf16(pf, vf, o[fd], 0, 0, 0);
      }
    }
  }
  float colsum[4] = {0.f, 0.f, 0.f, 0.f};
#pragma unroll
  for (int fd = 0; fd < 4; fd++)
#pragma unroll
    for (int r = 0; r < 4; r++) {
      int q = q0 + quad * 4 + r;
      float v = o[fd][r] / l_r[r];
      if (q >= ql) v = 0.f;
      size_t idx = (size_t)(b * 512 + q) * 512 + h * 64 + fd * 16 + cl;
      v += bf2f(qin[idx]);
      resout[idx] = f2bf(v);
      colsum[fd] += v;
    }
#pragma unroll
  for (int fd = 0; fd < 4; fd++) {
    colsum[fd] += __shfl_xor(colsum[fd], 16);
    colsum[fd] += __shfl_xor(colsum[fd], 32);
  }
  if (quad == 0) {
#pragma unroll
    for (int fd = 0; fd < 4; fd++) Csum[w][fd * 16 + cl] = colsum[fd];
  }
  __syncthreads();
  if (tid < 64) {
    float t = Csum[0][tid] + Csum[1][tid] + Csum[2][tid] + Csum[3][tid];
    atomicAdd(outp + b * 512 + h * 64 + tid, t * (1.0f / 512.0f));
  }
}

// ---------------- launch ----------------
extern "C" void kernel_launch(void* const* d_in, const int* in_sizes, int n_in,
                              void* d_out, int out_size, void* d_ws, size_t ws_size,
                              hipStream_t stream) {
  const float* queries = (const float*)d_in[0];
  const float* keys = (const float*)d_in[1];
  const int* qlen = (const int*)d_in[2];
  const int* klen = (const int*)d_in[3];
  const float* W_Q = (const float*)d_in[4];
  const float* W_K = (const float*)d_in[5];
  const float* W_V = (const float*)d_in[6];
  const float* fw1 = (const float*)d_in[7];
  const float* fw2 = (const float*)d_in[8];
  float* outp = (float*)d_out;
  char* ws = (char*)d_ws;

  constexpr size_t SZ_W = 512 * 512 * 2;
  constexpr size_t SZ_F = 2048 * 512 * 2;
  constexpr size_t SZ_S = 64 * 2048 * 4;               // 512 KB fp32 relu col-sums
  constexpr size_t SZ_T = (size_t)64 * 512 * 512 * 2;  // 32 MB bf16
  size_t o_WqT = 0;
  size_t o_WkT = o_WqT + SZ_W;
  size_t o_WvT = o_WkT + SZ_W;
  size_t o_F1T = o_WvT + SZ_W;
  size_t o_SUM = o_F1T + SZ_F;
  size_t o_ABCD = o_SUM + SZ_S;
  size_t o_E = o_ABCD + 4 * SZ_T;
  size_t NEED = o_E + SZ_T;
  if (ws_size < NEED) return;

  u16* WqT = (u16*)(ws + o_WqT);
  u16* WkT = (u16*)(ws + o_WkT);
  u16* WvT = (u16*)(ws + o_WvT);
  u16* F1T = (u16*)(ws + o_F1T);
  float* sums = (float*)(ws + o_SUM);
  u16* q_in = (u16*)(ws + o_ABCD);
  u16* k_in = (u16*)(ws + o_ABCD + SZ_T);
  u16* qp = (u16*)(ws + o_ABCD + 2 * SZ_T);
  u16* kpb = (u16*)(ws + o_ABCD + 3 * SZ_T);
  u16* vT = k_in;
  u16* resb = (u16*)(ws + o_E);

  hipMemsetAsync(d_out, 0, (size_t)out_size * sizeof(float), stream);
  hipMemsetAsync(sums, 0, SZ_S, stream);

  dim3 tb(32, 8);
  wtrans_kernel<<<dim3(16, 16), tb, 0, stream>>>(W_Q, WqT, 512, 512);
  wtrans_kernel<<<dim3(16, 16), tb, 0, stream>>>(W_K, WkT, 512, 512);
  wtrans_kernel<<<dim3(16, 16), tb, 0, stream>>>(W_V, WvT, 512, 512);
  wtrans_kernel<<<dim3(64, 16), tb, 0, stream>>>(fw1, F1T, 512, 2048);

  pe_add_kernel<<<16384, 256, 0, stream>>>(queries, keys, q_in, k_in);

  // fused dual dispatch: first half qp = q_in@WqT^T, second half kpb = k_in@WkT^T
  gemm_bt<0, 1><<<2 * 4 * 256, 256, 0, stream>>>(q_in, WqT, qp, 4, 1, 512, 512, nullptr, k_in, WkT, kpb);
  gemm_bt<3, 0><<<4 * 256, 256, 0, stream>>>(kpb, WvT, vT, 4, 1, 512, 512, nullptr, nullptr, nullptr, nullptr);

  attn_kernel<<<4096, 256, 0, stream>>>(qp, kpb, vT, q_in, resb, qlen, klen, outp);

  // FFN1: relu col-sums only (h1 never materialized)
  gemm_bt<2, 0><<<16 * 256, 256, 0, stream>>>(resb, F1T, nullptr, 16, 1, 2048, 512, sums, nullptr, nullptr, nullptr);
  // FFN2 collapsed to (sums/512) @ fw2
  ffn2_mean_kernel<<<64, 256, 0, stream>>>(sums, fw2, outp);
}

// Round 7
// 430.587 us; speedup vs baseline: 1.2575x; 1.2575x over previous
//
#include <hip/hip_runtime.h>

typedef unsigned short u16;
typedef __attribute__((ext_vector_type(8))) short short8;
typedef __attribute__((ext_vector_type(4))) float floatx4;

#define LOG2E 1.44269504f

__device__ __forceinline__ u16 f2bf(float x) {
  union { float f; unsigned u; } un; un.f = x;
  unsigned r = un.u + 0x7fffu + ((un.u >> 16) & 1u);
  return (u16)(r >> 16);
}
__device__ __forceinline__ float bf2f(u16 h) {
  union { unsigned u; float f; } un; un.u = ((unsigned)h) << 16;
  return un.f;
}
__device__ __forceinline__ void gld16(const u16* g, u16* l) {
  __builtin_amdgcn_global_load_lds((__attribute__((address_space(1))) void*)g,
                                   (__attribute__((address_space(3))) void*)l, 16, 0, 0);
}

// ---------------- weight transpose + fp32->bf16 : in (K,N) -> out (N,K) ----------------
__global__ __launch_bounds__(256) void wtrans_kernel(const float* __restrict__ in,
                                                     u16* __restrict__ out, int K, int N) {
  __shared__ float tile[32][33];
  int tx = threadIdx.x, ty = threadIdx.y;
  int n0 = blockIdx.x * 32, k0 = blockIdx.y * 32;
#pragma unroll
  for (int i = 0; i < 4; i++) {
    int kk = ty + i * 8;
    tile[kk][tx] = in[(size_t)(k0 + kk) * N + n0 + tx];
  }
  __syncthreads();
#pragma unroll
  for (int i = 0; i < 4; i++) {
    int nn = ty + i * 8;
    out[(size_t)(n0 + nn) * K + k0 + tx] = f2bf(tile[tx][nn]);
  }
}

// ---------------- PE add: q_in = bf16(q + pe), k_in = bf16(k + pe) ----------------
__global__ __launch_bounds__(256) void pe_add_kernel(const float* __restrict__ q,
                                                     const float* __restrict__ k,
                                                     u16* __restrict__ qb, u16* __restrict__ kb) {
  size_t flat = ((size_t)blockIdx.x * 256 + threadIdx.x) * 4;
  int d0 = (int)(flat & 511);
  int t = (int)((flat >> 9) & 511);
  const float4 qv = *(const float4*)(q + flat);
  const float4 kv = *(const float4*)(k + flat);
  float pe[4];
#pragma unroll
  for (int i = 0; i < 4; i++) {
    int d = d0 + i;
    int j = (d < 256) ? d : d - 256;
    float f = exp2f((float)j * -0.05190512648f);  // -log2(10000)/256
    float arg = (float)t * f;
    pe[i] = (d < 256) ? cosf(arg) : sinf(arg);
  }
  u16 qo[4], ko[4];
  qo[0] = f2bf(qv.x + pe[0]); qo[1] = f2bf(qv.y + pe[1]);
  qo[2] = f2bf(qv.z + pe[2]); qo[3] = f2bf(qv.w + pe[3]);
  ko[0] = f2bf(kv.x + pe[0]); ko[1] = f2bf(kv.y + pe[1]);
  ko[2] = f2bf(kv.z + pe[2]); ko[3] = f2bf(kv.w + pe[3]);
  *(uint2*)(qb + flat) = *(const uint2*)qo;
  *(uint2*)(kb + flat) = *(const uint2*)ko;
}

// ---------------- bf16 GEMM, BK=64: C = A(MxK) @ Bt(NxK)^T ----------------
// 1-D grid, XCD-swizzled; optional split-K (KS slices).
// DUAL: second half of grid computes C2 = A2 @ Bt2 (independent problem, same shape).
// EPI: 0 = store bf16 C; 2 = relu + column-sum -> atomicAdd outp[b*N + col] (no C store);
//      3 = store transposed per-head: C[((b*8+h)*64+d)*512 + s]  (V^T for attention)
template <int EPI, int DUAL>
__global__ __launch_bounds__(256) void gemm_bt(const u16* __restrict__ A, const u16* __restrict__ Bt,
                                               u16* __restrict__ C, int NX, int KS, int N, int K,
                                               float* __restrict__ outp,
                                               const u16* __restrict__ A2, const u16* __restrict__ Bt2,
                                               u16* __restrict__ C2) {
  __shared__ u16 Alds[128 * 64];
  __shared__ u16 Blds[128 * 64];
  const int tid = threadIdx.x;
  const int lane = tid & 63, w = tid >> 6;
  const int quad = lane >> 4, cl = lane & 15;
  const int wm = w >> 1, wn = w & 1;
  int L = blockIdx.x;
  if (DUAL) {
    int half = gridDim.x >> 1;
    if (L >= half) { L -= half; A = A2; Bt = Bt2; C = C2; }
  }
  const int xcd = L & 7, s = L >> 3;
  const int nx = s % NX;
  const int t2 = s / NX;
  const int ksl = t2 % KS;
  const int rgrp = t2 / KS;
  const int tm = (rgrp * 8 + xcd) * 128;
  const int tn = nx * 128;
  const int kbase = ksl * (K / KS);
  floatx4 acc[4][4] = {};
  const int nk = (K / KS) >> 6;
  const int srow = lane >> 3;        // row within 8-row chunk
  const int sg = (lane & 7) ^ srow;  // swizzled global K-group
  for (int ks = 0; ks < nk; ks++) {
    __syncthreads();
    const int k0 = kbase + (ks << 6);
#pragma unroll
    for (int i = 0; i < 4; i++) {
      int c = w * 4 + i;
      int row = c * 8 + srow;
      gld16(A + ((size_t)(tm + row) * K + k0 + sg * 8), &Alds[c * 512]);
      gld16(Bt + ((size_t)(tn + row) * K + k0 + sg * 8), &Blds[c * 512]);
    }
    __syncthreads();
#pragma unroll
    for (int kh = 0; kh < 2; kh++) {
      short8 af[4], bfr[4];
      const int ga = (((kh << 2) + quad) ^ (cl & 7)) * 8;
#pragma unroll
      for (int f = 0; f < 4; f++) {
        af[f] = *(const short8*)&Alds[(wm * 64 + f * 16 + cl) * 64 + ga];
        bfr[f] = *(const short8*)&Blds[(wn * 64 + f * 16 + cl) * 64 + ga];
      }
#pragma unroll
      for (int fm = 0; fm < 4; fm++)
#pragma unroll
        for (int fn = 0; fn < 4; fn++)
          acc[fm][fn] = __builtin_amdgcn_mfma_f32_16x16x32_bf16(af[fm], bfr[fn], acc[fm][fn], 0, 0, 0);
    }
  }
  if constexpr (EPI == 0) {
#pragma unroll
    for (int fm = 0; fm < 4; fm++)
#pragma unroll
      for (int fn = 0; fn < 4; fn++)
#pragma unroll
        for (int r = 0; r < 4; r++) {
          int row = tm + wm * 64 + fm * 16 + quad * 4 + r;
          int col = tn + wn * 64 + fn * 16 + cl;
          C[(size_t)row * N + col] = f2bf(acc[fm][fn][r]);
        }
  } else if constexpr (EPI == 2) {
    // relu + column-sum over this block's 128 rows -> atomicAdd into outp[b*N + col]
    __shared__ float red[256];
    float csum[4] = {0.f, 0.f, 0.f, 0.f};
#pragma unroll
    for (int fm = 0; fm < 4; fm++)
#pragma unroll
      for (int fn = 0; fn < 4; fn++)
#pragma unroll
        for (int r = 0; r < 4; r++) csum[fn] += fmaxf(acc[fm][fn][r], 0.0f);
#pragma unroll
    for (int fn = 0; fn < 4; fn++) {
      csum[fn] += __shfl_xor(csum[fn], 16);
      csum[fn] += __shfl_xor(csum[fn], 32);
    }
    __syncthreads();
    if (quad == 0) {
#pragma unroll
      for (int fn = 0; fn < 4; fn++) red[wm * 128 + wn * 64 + fn * 16 + cl] = csum[fn];
    }
    __syncthreads();
    if (tid < 128) {
      int wn2 = tid >> 6, c2 = tid & 63;
      float tot = red[wn2 * 64 + c2] + red[128 + wn2 * 64 + c2];
      int b = tm >> 9;
      atomicAdd(outp + (size_t)b * N + tn + wn2 * 64 + c2, tot);
    }
  } else {  // EPI == 3: transposed per-head store (V^T)
    __shared__ u16 Tr[128][130];
#pragma unroll
    for (int fm = 0; fm < 4; fm++)
#pragma unroll
      for (int fn = 0; fn < 4; fn++)
#pragma unroll
        for (int r = 0; r < 4; r++) {
          int row = wm * 64 + fm * 16 + quad * 4 + r;
          int col = wn * 64 + fn * 16 + cl;
          Tr[col][row] = f2bf(acc[fm][fn][r]);
        }
    __syncthreads();
    int col = tid >> 1, half = tid & 1;
    int b = tm >> 9, gcol = tn + col;
    int h = gcol >> 6, d = gcol & 63;
    int s0 = (tm & 511) + half * 64;
    u16* dst = C + ((size_t)((b * 8 + h) * 64 + d) * 512 + s0);
    const u16* src = &Tr[col][half * 64];
#pragma unroll
    for (int j = 0; j < 8; j++) *(short8*)(dst + j * 8) = *(const short8*)(src + j * 8);
  }
}

// ---------------- ffn2 via mean-commutation, f-split 16 ways ----------------
// block = (b, fs): accumulate (sums[b, fs*128:(fs+1)*128] @ fw2[slice]) into outp[b,:].
// fs in low 4 bits of blockIdx -> each fw2 slice pinned to one XCD's L2.
__global__ __launch_bounds__(256) void ffn2_mean_kernel(const float* __restrict__ sums,
                                                        const float* __restrict__ fw2,
                                                        float* __restrict__ outp) {
  __shared__ float s[128];
  int fs = blockIdx.x & 15, b = blockIdx.x >> 4;
  int tid = threadIdx.x;
  if (tid < 128) s[tid] = sums[(size_t)b * 2048 + fs * 128 + tid];
  __syncthreads();
  const float* w = fw2 + (size_t)(fs * 128) * 512;
  float a0 = 0.f, a1 = 0.f;
#pragma unroll 4
  for (int f = 0; f < 128; f++) {
    float sv = s[f];
    a0 += sv * w[(size_t)f * 512 + tid];
    a1 += sv * w[(size_t)f * 512 + 256 + tid];
  }
  atomicAdd(outp + b * 512 + tid, a0 * (1.0f / 512.0f));
  atomicAdd(outp + b * 512 + 256 + tid, a1 * (1.0f / 512.0f));
}

// ---------------- flash attention + residual + column-sum of result into outp ----------------
__global__ __launch_bounds__(256) void attn_kernel(const u16* __restrict__ qp, const u16* __restrict__ kp,
                                                   const u16* __restrict__ vT, const u16* __restrict__ qin,
                                                   u16* __restrict__ resout, const int* __restrict__ qlen,
                                                   const int* __restrict__ klen, float* __restrict__ outp) {
  __shared__ u16 Klds[128 * 64];
  __shared__ u16 Vlds[64 * 128];
  __shared__ u16 Plds[4][16 * 136];
  __shared__ float Csum[4][64];
  int bid = blockIdx.x;
  int qt = bid & 7, h = (bid >> 3) & 7, b = bid >> 6;
  int tid = threadIdx.x, lane = tid & 63, w = tid >> 6;
  int quad = lane >> 4, cl = lane & 15;
  int kl = klen[b], ql = qlen[b];
  int q0 = qt * 64 + w * 16;

  if (qt * 64 >= ql) {
    int c = tid & 63, r0 = (tid >> 6) * 16;
    float s = 0.f;
#pragma unroll
    for (int i = 0; i < 16; i++) {
      size_t idx = ((size_t)(b * 512 + qt * 64 + r0 + i) * 512) + h * 64 + c;
      u16 val = qin[idx];
      resout[idx] = val;
      s += bf2f(val);
    }
    Csum[w][c] = s;
    __syncthreads();
    if (tid < 64) {
      float t = Csum[0][tid] + Csum[1][tid] + Csum[2][tid] + Csum[3][tid];
      atomicAdd(outp + b * 512 + h * 64 + tid, t * (1.0f / 512.0f));
    }
    return;
  }
  bool wactive = q0 < ql;

  short8 qfrag[2];
#pragma unroll
  for (int ks = 0; ks < 2; ks++)
    qfrag[ks] = *(const short8*)(qp + ((size_t)(b * 512 + q0 + cl) * 512 + h * 64 + ks * 32 + quad * 8));
  float m_r[4], l_r[4];
  floatx4 o[4] = {};
#pragma unroll
  for (int r = 0; r < 4; r++) { m_r[r] = -3.0e38f; l_r[r] = 0.f; }

  int nkt = (kl + 127) >> 7;
  for (int kt = 0; kt < nkt; kt++) {
    __syncthreads();
#pragma unroll
    for (int i = 0; i < 4; i++) {
      int c = w * 4 + i;
      int row = c * 8 + (lane >> 3);
      int gc = (lane & 7) ^ (row & 7);
      gld16(kp + ((size_t)(b * 512 + kt * 128 + row) * 512 + h * 64 + gc * 8), &Klds[c * 512]);
    }
#pragma unroll
    for (int i = 0; i < 4; i++) {
      int c = w * 4 + i;
      int row = c * 4 + (lane >> 4);
      int gc = (lane & 15) ^ (row & 7);
      gld16(vT + ((size_t)((b * 8 + h) * 64 + row) * 512 + kt * 128 + gc * 8), &Vlds[c * 512]);
    }
    __syncthreads();
    if (!wactive) continue;
    floatx4 sacc[8] = {};
#pragma unroll
    for (int f = 0; f < 8; f++) {
      int krow = f * 16 + cl;
#pragma unroll
      for (int ks = 0; ks < 2; ks++) {
        int kc = ks * 4 + quad;
        short8 kf = *(const short8*)&Klds[krow * 64 + ((kc ^ (cl & 7)) * 8)];
        sacc[f] = __builtin_amdgcn_mfma_f32_16x16x32_bf16(qfrag[ks], kf, sacc[f], 0, 0, 0);
      }
    }
    float mnew[4];
#pragma unroll
    for (int r = 0; r < 4; r++) mnew[r] = m_r[r];
#pragma unroll
    for (int f = 0; f < 8; f++) {
      int key = kt * 128 + f * 16 + cl;
      bool ok = key < kl;
#pragma unroll
      for (int r = 0; r < 4; r++) {
        float v = ok ? sacc[f][r] * 0.125f : -4294967296.0f;
        sacc[f][r] = v;
        mnew[r] = fmaxf(mnew[r], v);
      }
    }
#pragma unroll
    for (int mk = 1; mk <= 8; mk <<= 1)
#pragma unroll
      for (int r = 0; r < 4; r++) mnew[r] = fmaxf(mnew[r], __shfl_xor(mnew[r], mk));
    float alpha[4], lad[4];
#pragma unroll
    for (int r = 0; r < 4; r++) {
      alpha[r] = exp2f((m_r[r] - mnew[r]) * LOG2E);
      lad[r] = 0.f;
      m_r[r] = mnew[r];
    }
#pragma unroll
    for (int f = 0; f < 8; f++)
#pragma unroll
      for (int r = 0; r < 4; r++) {
        float p = exp2f((sacc[f][r] - mnew[r]) * LOG2E);
        lad[r] += p;
        Plds[w][(quad * 4 + r) * 136 + f * 16 + cl] = f2bf(p);
      }
#pragma unroll
    for (int mk = 1; mk <= 8; mk <<= 1)
#pragma unroll
      for (int r = 0; r < 4; r++) lad[r] += __shfl_xor(lad[r], mk);
#pragma unroll
    for (int r = 0; r < 4; r++) l_r[r] = l_r[r] * alpha[r] + lad[r];
#pragma unroll
    for (int fd = 0; fd < 4; fd++)
#pragma unroll
      for (int r = 0; r < 4; r++) o[fd][r] *= alpha[r];
#pragma unroll
    for (int k2 = 0; k2 < 4; k2++) {
      short8 pf = *(const short8*)&Plds[w][cl * 136 + k2 * 32 + quad * 8];
#pragma unroll
      for (int fd = 0; fd < 4; fd++) {
        int vrow = fd * 16 + cl;
        int sc = k2 * 4 + quad;
        short8 vf = *(const short8*)&Vlds[vrow * 128 + ((sc ^ (cl & 7)) * 8)];
        o[fd] = __builtin_amdgcn_mfma_f32_16x16x32_bf16(pf, vf, o[fd], 0, 0, 0);
      }
    }
  }
  float colsum[4] = {0.f, 0.f, 0.f, 0.f};
#pragma unroll
  for (int fd = 0; fd < 4; fd++)
#pragma unroll
    for (int r = 0; r < 4; r++) {
      int q = q0 + quad * 4 + r;
      float v = o[fd][r] / l_r[r];
      if (q >= ql) v = 0.f;
      size_t idx = (size_t)(b * 512 + q) * 512 + h * 64 + fd * 16 + cl;
      v += bf2f(qin[idx]);
      resout[idx] = f2bf(v);
      colsum[fd] += v;
    }
#pragma unroll
  for (int fd = 0; fd < 4; fd++) {
    colsum[fd] += __shfl_xor(colsum[fd], 16);
    colsum[fd] += __shfl_xor(colsum[fd], 32);
  }
  if (quad == 0) {
#pragma unroll
    for (int fd = 0; fd < 4; fd++) Csum[w][fd * 16 + cl] = colsum[fd];
  }
  __syncthreads();
  if (tid < 64) {
    float t = Csum[0][tid] + Csum[1][tid] + Csum[2][tid] + Csum[3][tid];
    atomicAdd(outp + b * 512 + h * 64 + tid, t * (1.0f / 512.0f));
  }
}

// ---------------- launch ----------------
extern "C" void kernel_launch(void* const* d_in, const int* in_sizes, int n_in,
                              void* d_out, int out_size, void* d_ws, size_t ws_size,
                              hipStream_t stream) {
  const float* queries = (const float*)d_in[0];
  const float* keys = (const float*)d_in[1];
  const int* qlen = (const int*)d_in[2];
  const int* klen = (const int*)d_in[3];
  const float* W_Q = (const float*)d_in[4];
  const float* W_K = (const float*)d_in[5];
  const float* W_V = (const float*)d_in[6];
  const float* fw1 = (const float*)d_in[7];
  const float* fw2 = (const float*)d_in[8];
  float* outp = (float*)d_out;
  char* ws = (char*)d_ws;

  constexpr size_t SZ_W = 512 * 512 * 2;
  constexpr size_t SZ_F = 2048 * 512 * 2;
  constexpr size_t SZ_S = 64 * 2048 * 4;               // 512 KB fp32 relu col-sums
  constexpr size_t SZ_T = (size_t)64 * 512 * 512 * 2;  // 32 MB bf16
  size_t o_WqT = 0;
  size_t o_WkT = o_WqT + SZ_W;
  size_t o_WvT = o_WkT + SZ_W;
  size_t o_F1T = o_WvT + SZ_W;
  size_t o_SUM = o_F1T + SZ_F;
  size_t o_ABCD = o_SUM + SZ_S;
  size_t o_E = o_ABCD + 4 * SZ_T;
  size_t NEED = o_E + SZ_T;
  if (ws_size < NEED) return;

  u16* WqT = (u16*)(ws + o_WqT);
  u16* WkT = (u16*)(ws + o_WkT);
  u16* WvT = (u16*)(ws + o_WvT);
  u16* F1T = (u16*)(ws + o_F1T);
  float* sums = (float*)(ws + o_SUM);
  u16* q_in = (u16*)(ws + o_ABCD);
  u16* k_in = (u16*)(ws + o_ABCD + SZ_T);
  u16* qp = (u16*)(ws + o_ABCD + 2 * SZ_T);
  u16* kpb = (u16*)(ws + o_ABCD + 3 * SZ_T);
  u16* vT = k_in;
  u16* resb = (u16*)(ws + o_E);

  hipMemsetAsync(d_out, 0, (size_t)out_size * sizeof(float), stream);
  hipMemsetAsync(sums, 0, SZ_S, stream);

  dim3 tb(32, 8);
  wtrans_kernel<<<dim3(16, 16), tb, 0, stream>>>(W_Q, WqT, 512, 512);
  wtrans_kernel<<<dim3(16, 16), tb, 0, stream>>>(W_K, WkT, 512, 512);
  wtrans_kernel<<<dim3(16, 16), tb, 0, stream>>>(W_V, WvT, 512, 512);
  wtrans_kernel<<<dim3(64, 16), tb, 0, stream>>>(fw1, F1T, 512, 2048);

  pe_add_kernel<<<16384, 256, 0, stream>>>(queries, keys, q_in, k_in);

  // fused dual dispatch: first half qp = q_in@WqT^T, second half kpb = k_in@WkT^T
  gemm_bt<0, 1><<<2 * 4 * 256, 256, 0, stream>>>(q_in, WqT, qp, 4, 1, 512, 512, nullptr, k_in, WkT, kpb);
  gemm_bt<3, 0><<<4 * 256, 256, 0, stream>>>(kpb, WvT, vT, 4, 1, 512, 512, nullptr, nullptr, nullptr, nullptr);

  attn_kernel<<<4096, 256, 0, stream>>>(qp, kpb, vT, q_in, resb, qlen, klen, outp);

  // FFN1: relu col-sums only (h1 never materialized)
  gemm_bt<2, 0><<<16 * 256, 256, 0, stream>>>(resb, F1T, nullptr, 16, 1, 2048, 512, sums, nullptr, nullptr, nullptr);
  // FFN2 collapsed to (sums/512) @ fw2, f-split 16 ways
  ffn2_mean_kernel<<<1024, 256, 0, stream>>>(sums, fw2, outp);
}